// Round 1
// baseline (1206.676 us; speedup 1.0000x reference)
//
#include <hip/hip_runtime.h>

// ---------------------------------------------------------------------------
// TFN-lite layer, MI355X fp32 implementation.
//
// Math (per edge e, row=r, col=c):
//   ev = pos[r]-pos[c]; d = sqrt(|ev|^2 + 1e-12); n = ev/d
//   rbf[i] = exp(-4.5*(d - i/3)^2), i=0..15
//   h = relu(rbf @ W1) * 0.25                       (64)
//   w = h @ W2 * 0.125                              (576)  -- never materialized
//   out_s[wo]    = a0 * sum_u ( A'[u,wo]*xs[u] + B'[u,wo]*(xv[u].n) )
//   out_v[wo][k] = a1 * sum_u ( C'[u,wo]*xs[u]*n[k] + D'[u,wo]*xv[u][k]/S3
//                              + E[u,wo]*(M xv[u])[k] )
// where A' = wA[:,0,:]+wA[:,1,:] etc (v-folded, edge-independent -> prep kernel)
// and M[k][i] = sum_j cg121[k,i,j]*Y2[j].
// y = segment_sum(out, row); out[:, :8] = silu(y[:, :8]).
// ---------------------------------------------------------------------------

#define INV_S3  0.5773502691896258f   // 1/sqrt(3)
#define A0S     0.1767766952966369f   // 1/sqrt(32)
#define A1S     0.27386127875258306f  // sqrt(3)/sqrt(40)
#define S15     3.872983346207417f    // sqrt(15)
#define S5      2.23606797749979f     // sqrt(5)
#define INV_S10 0.31622776601683794f  // 1/sqrt(10)   (cg121 normalized)
#define INV_S30 0.18257418583505536f  // 1/sqrt(30)

#define BLK 128

// Fold W2 (64x576) into W2f laid out [k][u*40 + t*8 + wo], 64 rows x 320 cols.
// t=0:A' 1:B' 2:C' 3:D' (v-summed pairs), 4:E (copy).
__global__ void prep_w2(const float* __restrict__ W2, float* __restrict__ W2f) {
    int idx = blockIdx.x * blockDim.x + threadIdx.x;
    if (idx >= 64 * 320) return;
    int k = idx / 320;
    int c = idx - k * 320;
    int u = c / 40;
    int r = c - u * 40;
    int t = r >> 3;
    int wo = r & 7;
    const float* Wk = W2 + k * 576;
    float v;
    if (t < 4) {
        int base = t * 128 + u * 16 + wo;
        v = Wk[base] + Wk[base + 8];
    } else {
        v = Wk[512 + u * 8 + wo];
    }
    W2f[idx] = v;
}

__global__ __launch_bounds__(BLK, 2) void tfn_edge(
    const float* __restrict__ x, const float* __restrict__ pos,
    const int* __restrict__ ei, const float* __restrict__ W1,
    const float* __restrict__ W2f, float* __restrict__ y, int E) {
    // h per thread lives in LDS; stride 65 floats -> (tid+k)%32 banks, only the
    // free 2-way wave64 aliasing.
    __shared__ float hs[BLK * 65];

    int e = blockIdx.x * BLK + threadIdx.x;
    if (e >= E) return;

    int row = ei[e];
    int col = ei[E + e];

    float evx = pos[3 * row + 0] - pos[3 * col + 0];
    float evy = pos[3 * row + 1] - pos[3 * col + 1];
    float evz = pos[3 * row + 2] - pos[3 * col + 2];
    float d2 = evx * evx + evy * evy + evz * evz + 1e-12f;
    float d = sqrtf(d2);
    float invd = 1.0f / d;
    float nx = evx * invd, ny = evy * invd, nz = evz * invd;

    // ---- h = relu(rbf @ W1) * 0.25 (W1 reads are wave-uniform -> s_load) ----
    float h[64];
#pragma unroll
    for (int c2 = 0; c2 < 64; ++c2) h[c2] = 0.f;
#pragma unroll 1
    for (int i = 0; i < 16; ++i) {
        float t = d - (float)i * (1.0f / 3.0f);
        float r = __expf(-4.5f * t * t);
        const float* w1p = W1 + i * 64;
#pragma unroll
        for (int c2 = 0; c2 < 64; ++c2) h[c2] = fmaf(r, w1p[c2], h[c2]);
    }
    float* hrow = hs + threadIdx.x * 65;
#pragma unroll
    for (int c2 = 0; c2 < 64; ++c2) hrow[c2] = fmaxf(h[c2], 0.f) * 0.25f;
    // (thread-private LDS row: no barrier needed)

    // ---- per-edge features ----
    const float4* xr4 = reinterpret_cast<const float4*>(x + row * 32);
    float4 t0 = xr4[0], t1 = xr4[1];
    float xs[8] = {t0.x, t0.y, t0.z, t0.w, t1.x, t1.y, t1.z, t1.w};
    float xv[24];
    {
        float4 v0_ = xr4[2], v1_ = xr4[3], v2_ = xr4[4], v3_ = xr4[5], v4_ = xr4[6], v5_ = xr4[7];
        xv[0] = v0_.x;  xv[1] = v0_.y;  xv[2] = v0_.z;  xv[3] = v0_.w;
        xv[4] = v1_.x;  xv[5] = v1_.y;  xv[6] = v1_.z;  xv[7] = v1_.w;
        xv[8] = v2_.x;  xv[9] = v2_.y;  xv[10] = v2_.z; xv[11] = v2_.w;
        xv[12] = v3_.x; xv[13] = v3_.y; xv[14] = v3_.z; xv[15] = v3_.w;
        xv[16] = v4_.x; xv[17] = v4_.y; xv[18] = v4_.z; xv[19] = v4_.w;
        xv[20] = v5_.x; xv[21] = v5_.y; xv[22] = v5_.z; xv[23] = v5_.w;
    }

    // ---- M = cg121 . Y2(n)  (symmetric 3x3) ----
    float Y20 = S15 * nx * nz;
    float Y21 = S15 * nx * ny;
    float Y22 = 0.5f * S5 * (3.f * ny * ny - 1.f);
    float Y23 = S15 * ny * nz;
    float Y24 = 0.5f * S15 * (nz * nz - nx * nx);
    float M00 = -Y22 * INV_S30 - Y24 * INV_S10;
    float M11 = 2.f * Y22 * INV_S30;
    float M22 = -Y22 * INV_S30 + Y24 * INV_S10;
    float M01 = Y21 * INV_S10;
    float M02 = Y20 * INV_S10;
    float M12 = Y23 * INV_S10;

    float s_acc[8], v0[8], v1[8], v2[8];
#pragma unroll
    for (int wo = 0; wo < 8; ++wo) { s_acc[wo] = 0.f; v0[wo] = 0.f; v1[wo] = 0.f; v2[wo] = 0.f; }

    // ---- main loop: per u, dot h against 40 folded columns, contract ----
#pragma unroll
    for (int u = 0; u < 8; ++u) {
        float wa[40];
#pragma unroll
        for (int t = 0; t < 40; ++t) wa[t] = 0.f;
        const float* wp = W2f + u * 40;
#pragma unroll 2
        for (int k = 0; k < 64; ++k) {
            float hk = hrow[k];
            const float* p = wp + k * 320;  // wave-uniform address -> s_load
#pragma unroll
            for (int t = 0; t < 40; ++t) wa[t] = fmaf(hk, p[t], wa[t]);
        }
        float xu = xs[u];
        float a = xv[u * 3 + 0], b = xv[u * 3 + 1], c3 = xv[u * 3 + 2];
        float qu = a * nx + b * ny + c3 * nz;          // (xv[u].Y1)/S3
        float m0 = M00 * a + M01 * b + M02 * c3;
        float m1 = M01 * a + M11 * b + M12 * c3;
        float m2 = M02 * a + M12 * b + M22 * c3;
#pragma unroll
        for (int wo = 0; wo < 8; ++wo) {
            s_acc[wo] = fmaf(xu, wa[wo], s_acc[wo]);
            s_acc[wo] = fmaf(qu, wa[8 + wo], s_acc[wo]);
            float cw = xu * wa[16 + wo];
            v0[wo] = fmaf(cw, nx, v0[wo]);
            v1[wo] = fmaf(cw, ny, v1[wo]);
            v2[wo] = fmaf(cw, nz, v2[wo]);
            float wd = INV_S3 * wa[24 + wo];
            v0[wo] = fmaf(a, wd, v0[wo]);
            v1[wo] = fmaf(b, wd, v1[wo]);
            v2[wo] = fmaf(c3, wd, v2[wo]);
            float we = wa[32 + wo];
            v0[wo] = fmaf(m0, we, v0[wo]);
            v1[wo] = fmaf(m1, we, v1[wo]);
            v2[wo] = fmaf(m2, we, v2[wo]);
        }
    }

    // ---- segment-sum via atomics into y (= d_out, pre-zeroed) ----
    float* yr = y + row * 32;
#pragma unroll
    for (int wo = 0; wo < 8; ++wo) atomicAdd(yr + wo, A0S * 0.125f * s_acc[wo]);
#pragma unroll
    for (int wo = 0; wo < 8; ++wo) {
        atomicAdd(yr + 8 + wo * 3 + 0, A1S * 0.125f * v0[wo]);
        atomicAdd(yr + 8 + wo * 3 + 1, A1S * 0.125f * v1[wo]);
        atomicAdd(yr + 8 + wo * 3 + 2, A1S * 0.125f * v2[wo]);
    }
}

// In-place silu on first 8 columns of y (= d_out).
__global__ void finish_silu(float* __restrict__ y, int n8) {
    int i = blockIdx.x * blockDim.x + threadIdx.x;
    if (i >= n8) return;
    int rown = i >> 3, c = i & 7;
    int idx = rown * 32 + c;
    float v = y[idx];
    y[idx] = v / (1.0f + __expf(-v));
}

extern "C" void kernel_launch(void* const* d_in, const int* in_sizes, int n_in,
                              void* d_out, int out_size, void* d_ws, size_t ws_size,
                              hipStream_t stream) {
    const float* x   = (const float*)d_in[0];
    const float* pos = (const float*)d_in[1];
    const int*   ei  = (const int*)d_in[2];
    const float* W1  = (const float*)d_in[3];
    const float* W2  = (const float*)d_in[4];
    int N = in_sizes[1] / 3;
    int E = in_sizes[2] / 2;

    float* W2f = (float*)d_ws;          // 64*320*4 = 80 KiB
    float* y   = (float*)d_out;         // accumulate directly into output

    hipMemsetAsync(y, 0, (size_t)N * 32 * sizeof(float), stream);
    hipLaunchKernelGGL(prep_w2, dim3((64 * 320 + 255) / 256), dim3(256), 0, stream, W2, W2f);
    hipLaunchKernelGGL(tfn_edge, dim3((E + BLK - 1) / BLK), dim3(BLK), 0, stream,
                       x, pos, ei, W1, W2f, y, E);
    hipLaunchKernelGGL(finish_silu, dim3((N * 8 + 255) / 256), dim3(256), 0, stream, y, N * 8);
}

// Round 2
// 377.374 us; speedup vs baseline: 3.1976x; 3.1976x over previous
//
#include <hip/hip_runtime.h>

// ---------------------------------------------------------------------------
// TFN-lite layer, MI355X fp32 implementation, round 2.
//
// Key observations:
//  * w = h(d) @ W2 depends ONLY on the scalar distance d. After folding the
//    duplicated v-dimension (A'=wA[:,0]+wA[:,1] etc.), the per-edge weights
//    are 320 numbers wa(d). We tabulate wa on a 2048-point grid over [0,8]
//    (beyond d=7.3 all RBFs underflow to 0, so clamping is exact) and lerp.
//  * segment_sum via counting-sort CSR + contiguous gather instead of 12.8M
//    scattered fp32 global atomics (which caused 587 MB of HBM writes in R1).
// ---------------------------------------------------------------------------

#define INV_S3  0.5773502691896258f   // 1/sqrt(3)
#define A0S     0.1767766952966369f   // 1/sqrt(32)
#define A1S     0.27386127875258306f  // sqrt(3)/sqrt(40)
#define S15     3.872983346207417f    // sqrt(15)
#define S5      2.23606797749979f     // sqrt(5)
#define INV_S10 0.31622776601683794f  // 1/sqrt(10)   (cg121 normalized)
#define INV_S30 0.18257418583505536f  // 1/sqrt(30)

#define TBL   2048
#define DMAX  8.0f

// ---------------------------------------------------------------------------
// Fold W2 (64x576) into W2f [k][u*40 + t*8 + wo], 64 rows x 320 cols.
// t=0:A' 1:B' 2:C' 3:D' (v-summed pairs), 4:E (copy).
__global__ void prep_w2(const float* __restrict__ W2, float* __restrict__ W2f) {
    int idx = blockIdx.x * blockDim.x + threadIdx.x;
    if (idx >= 64 * 320) return;
    int k = idx / 320;
    int c = idx - k * 320;
    int u = c / 40;
    int r = c - u * 40;
    int t = r >> 3;
    int wo = r & 7;
    const float* Wk = W2 + k * 576;
    float v;
    if (t < 4) {
        int base = t * 128 + u * 16 + wo;
        v = Wk[base] + Wk[base + 8];
    } else {
        v = Wk[512 + u * 8 + wo];
    }
    W2f[idx] = v;
}

// T[j][c] = wa_c(d_j), d_j = j * DMAX/(TBL-1).  One block per j, 320 threads.
__global__ void build_table(const float* __restrict__ W1,
                            const float* __restrict__ W2f,
                            float* __restrict__ T) {
    __shared__ float hs[64];
    int j = blockIdx.x;
    float d = (float)j * (DMAX / (float)(TBL - 1));
    int tid = threadIdx.x;
    if (tid < 64) {
        float acc = 0.f;
#pragma unroll
        for (int i = 0; i < 16; ++i) {
            float t = d - (float)i * (1.0f / 3.0f);
            float r = __expf(-4.5f * t * t);
            acc = fmaf(r, W1[i * 64 + tid], acc);
        }
        hs[tid] = fmaxf(acc, 0.f) * 0.25f;   // /sqrt(16)
    }
    __syncthreads();
    float acc = 0.f;
#pragma unroll 4
    for (int k = 0; k < 64; ++k) acc = fmaf(hs[k], W2f[k * 320 + tid], acc);
    T[j * 320 + tid] = acc;
}

// ---------------------------------------------------------------------------
// CSR build: histogram -> single-block scan -> (cursor used by edge kernel)
__global__ void hist_rows(const int* __restrict__ ei, int* __restrict__ cnt, int E) {
    int e = blockIdx.x * blockDim.x + threadIdx.x;
    if (e < E) atomicAdd(&cnt[ei[e]], 1);
}

#define SCAN_NT 1024
#define SCAN_L  32   // covers n <= 32768
__global__ void scan_counts(const int* __restrict__ cnt, int* __restrict__ offs,
                            int* __restrict__ cur, int n) {
    __shared__ int sums[SCAN_NT];
    int tid = threadIdx.x;
    int start = tid * SCAN_L;
    int total = 0;
#pragma unroll 4
    for (int i = 0; i < SCAN_L; ++i) {
        int idx = start + i;
        total += (idx < n) ? cnt[idx] : 0;
    }
    sums[tid] = total;
    __syncthreads();
    // Hillis-Steele inclusive scan over 1024 totals
    for (int s = 1; s < SCAN_NT; s <<= 1) {
        int t = (tid >= s) ? sums[tid - s] : 0;
        __syncthreads();
        sums[tid] += t;
        __syncthreads();
    }
    int running = sums[tid] - total;   // exclusive prefix of this chunk
#pragma unroll 4
    for (int i = 0; i < SCAN_L; ++i) {
        int idx = start + i;
        if (idx < n) {
            offs[idx] = running;
            cur[idx] = running;
            running += cnt[idx];
        }
    }
}

// ---------------------------------------------------------------------------
// Per-edge compute shared by both tiers: table lerp + tensor contraction.
__device__ __forceinline__ void edge_compute(
    const float* __restrict__ x, const float* __restrict__ pos,
    const int* __restrict__ ei, const float* __restrict__ T,
    int e, int E, int& row_out, float out[32]) {

    int row = ei[e];
    int col = ei[E + e];
    row_out = row;

    float evx = pos[3 * row + 0] - pos[3 * col + 0];
    float evy = pos[3 * row + 1] - pos[3 * col + 1];
    float evz = pos[3 * row + 2] - pos[3 * col + 2];
    float d2 = evx * evx + evy * evy + evz * evz + 1e-12f;
    float d = sqrtf(d2);
    float invd = 1.0f / d;
    float nx = evx * invd, ny = evy * invd, nz = evz * invd;

    // table coords
    float fj = d * ((float)(TBL - 1) / DMAX);
    int j0 = (int)fj;
    if (j0 > TBL - 2) j0 = TBL - 2;
    float t = fminf(fj - (float)j0, 1.0f);
    const float* Arow = T + j0 * 320;
    const float* Brow = Arow + 320;

    // per-edge features
    const float4* xr4 = reinterpret_cast<const float4*>(x + row * 32);
    float4 t0 = xr4[0], t1 = xr4[1];
    float xs[8] = {t0.x, t0.y, t0.z, t0.w, t1.x, t1.y, t1.z, t1.w};
    float xv[24];
    {
        float4 v0_ = xr4[2], v1_ = xr4[3], v2_ = xr4[4], v3_ = xr4[5],
               v4_ = xr4[6], v5_ = xr4[7];
        xv[0] = v0_.x;  xv[1] = v0_.y;  xv[2] = v0_.z;  xv[3] = v0_.w;
        xv[4] = v1_.x;  xv[5] = v1_.y;  xv[6] = v1_.z;  xv[7] = v1_.w;
        xv[8] = v2_.x;  xv[9] = v2_.y;  xv[10] = v2_.z; xv[11] = v2_.w;
        xv[12] = v3_.x; xv[13] = v3_.y; xv[14] = v3_.z; xv[15] = v3_.w;
        xv[16] = v4_.x; xv[17] = v4_.y; xv[18] = v4_.z; xv[19] = v4_.w;
        xv[20] = v5_.x; xv[21] = v5_.y; xv[22] = v5_.z; xv[23] = v5_.w;
    }

    // M = cg121 . Y2(n)  (symmetric 3x3)
    float Y20 = S15 * nx * nz;
    float Y21 = S15 * nx * ny;
    float Y22 = 0.5f * S5 * (3.f * ny * ny - 1.f);
    float Y23 = S15 * ny * nz;
    float Y24 = 0.5f * S15 * (nz * nz - nx * nx);
    float M00 = -Y22 * INV_S30 - Y24 * INV_S10;
    float M11 = 2.f * Y22 * INV_S30;
    float M22 = -Y22 * INV_S30 + Y24 * INV_S10;
    float M01 = Y21 * INV_S10;
    float M02 = Y20 * INV_S10;
    float M12 = Y23 * INV_S10;

    float s_acc[8], v0[8], v1[8], v2[8];
#pragma unroll
    for (int wo = 0; wo < 8; ++wo) { s_acc[wo] = 0.f; v0[wo] = 0.f; v1[wo] = 0.f; v2[wo] = 0.f; }

#pragma unroll 2
    for (int u = 0; u < 8; ++u) {
        // lerp the 40 folded weights for this u
        float wa[40];
        const float4* A4 = reinterpret_cast<const float4*>(Arow + u * 40);
        const float4* B4 = reinterpret_cast<const float4*>(Brow + u * 40);
#pragma unroll
        for (int q = 0; q < 10; ++q) {
            float4 a = A4[q], b = B4[q];
            wa[q * 4 + 0] = fmaf(t, b.x - a.x, a.x);
            wa[q * 4 + 1] = fmaf(t, b.y - a.y, a.y);
            wa[q * 4 + 2] = fmaf(t, b.z - a.z, a.z);
            wa[q * 4 + 3] = fmaf(t, b.w - a.w, a.w);
        }
        float xu = xs[u];
        float a = xv[u * 3 + 0], b = xv[u * 3 + 1], c3 = xv[u * 3 + 2];
        float qu = a * nx + b * ny + c3 * nz;          // (xv[u].Y1)/S3
        float m0 = M00 * a + M01 * b + M02 * c3;
        float m1 = M01 * a + M11 * b + M12 * c3;
        float m2 = M02 * a + M12 * b + M22 * c3;
#pragma unroll
        for (int wo = 0; wo < 8; ++wo) {
            s_acc[wo] = fmaf(xu, wa[wo], s_acc[wo]);
            s_acc[wo] = fmaf(qu, wa[8 + wo], s_acc[wo]);
            float cw = xu * wa[16 + wo];
            v0[wo] = fmaf(cw, nx, v0[wo]);
            v1[wo] = fmaf(cw, ny, v1[wo]);
            v2[wo] = fmaf(cw, nz, v2[wo]);
            float wd = INV_S3 * wa[24 + wo];
            v0[wo] = fmaf(a, wd, v0[wo]);
            v1[wo] = fmaf(b, wd, v1[wo]);
            v2[wo] = fmaf(c3, wd, v2[wo]);
            float we = wa[32 + wo];
            v0[wo] = fmaf(m0, we, v0[wo]);
            v1[wo] = fmaf(m1, we, v1[wo]);
            v2[wo] = fmaf(m2, we, v2[wo]);
        }
    }
#pragma unroll
    for (int wo = 0; wo < 8; ++wo) out[wo] = A0S * 0.125f * s_acc[wo];
#pragma unroll
    for (int wo = 0; wo < 8; ++wo) {
        out[8 + wo * 3 + 0] = A1S * 0.125f * v0[wo];
        out[8 + wo * 3 + 1] = A1S * 0.125f * v1[wo];
        out[8 + wo * 3 + 2] = A1S * 0.125f * v2[wo];
    }
}

// Primary tier: write per-edge output to its sorted CSR slot (plain stores).
__global__ __launch_bounds__(256) void tfn_edge_sorted(
    const float* __restrict__ x, const float* __restrict__ pos,
    const int* __restrict__ ei, const float* __restrict__ T,
    int* __restrict__ cur, float* __restrict__ eout, int E) {
    int e = blockIdx.x * 256 + threadIdx.x;
    if (e >= E) return;
    int row;
    float out[32];
    edge_compute(x, pos, ei, T, e, E, row, out);
    int p = atomicAdd(&cur[row], 1);
    float4* dst = reinterpret_cast<float4*>(eout + (size_t)p * 32);
#pragma unroll
    for (int q = 0; q < 8; ++q)
        dst[q] = make_float4(out[q * 4], out[q * 4 + 1], out[q * 4 + 2], out[q * 4 + 3]);
}

// Sum each node's contiguous run, silu on first 8 channels.
__global__ void gather_nodes(const float* __restrict__ eout,
                             const int* __restrict__ offs,
                             const int* __restrict__ cnt,
                             float* __restrict__ y, int N) {
    int i = blockIdx.x * blockDim.x + threadIdx.x;
    if (i >= N * 32) return;
    int node = i >> 5, c = i & 31;
    int o = offs[node], k = cnt[node];
    float acc = 0.f;
    for (int q = 0; q < k; ++q) acc += eout[(size_t)(o + q) * 32 + c];
    if (c < 8) acc = acc / (1.f + __expf(-acc));
    y[i] = acc;
}

// Fallback tier (small ws): table-based compute + global atomics (R1 style).
__global__ __launch_bounds__(256) void tfn_edge_atomic(
    const float* __restrict__ x, const float* __restrict__ pos,
    const int* __restrict__ ei, const float* __restrict__ T,
    float* __restrict__ y, int E) {
    int e = blockIdx.x * 256 + threadIdx.x;
    if (e >= E) return;
    int row;
    float out[32];
    edge_compute(x, pos, ei, T, e, E, row, out);
    float* yr = y + row * 32;
#pragma unroll
    for (int q = 0; q < 32; ++q) atomicAdd(yr + q, out[q]);
}

__global__ void finish_silu(float* __restrict__ y, int n8) {
    int i = blockIdx.x * blockDim.x + threadIdx.x;
    if (i >= n8) return;
    int rown = i >> 3, c = i & 7;
    int idx = rown * 32 + c;
    float v = y[idx];
    y[idx] = v / (1.0f + __expf(-v));
}

// ---------------------------------------------------------------------------
extern "C" void kernel_launch(void* const* d_in, const int* in_sizes, int n_in,
                              void* d_out, int out_size, void* d_ws, size_t ws_size,
                              hipStream_t stream) {
    const float* x   = (const float*)d_in[0];
    const float* pos = (const float*)d_in[1];
    const int*   ei  = (const int*)d_in[2];
    const float* W1  = (const float*)d_in[3];
    const float* W2  = (const float*)d_in[4];
    int N = in_sizes[1] / 3;
    int E = in_sizes[2] / 2;

    char* ws = (char*)d_ws;
    size_t off = 0;
    float* W2f = (float*)(ws + off); off += (size_t)64 * 320 * 4;          // 80 KiB
    float* T   = (float*)(ws + off); off += (size_t)TBL * 320 * 4;         // 2.62 MB
    size_t off_tab_end = off;
    int* cnt  = (int*)(ws + off); off += (size_t)N * 4;
    int* offs = (int*)(ws + off); off += (size_t)N * 4;
    int* cur  = (int*)(ws + off); off += (size_t)N * 4;
    float* eout = (float*)(ws + off); off += (size_t)E * 32 * 4;           // 51.2 MB
    size_t need_full = off;

    float* y = (float*)d_out;

    hipLaunchKernelGGL(prep_w2, dim3((64 * 320 + 255) / 256), dim3(256), 0, stream, W2, W2f);
    hipLaunchKernelGGL(build_table, dim3(TBL), dim3(320), 0, stream, W1, W2f, T);

    if (ws_size >= need_full) {
        hipMemsetAsync(cnt, 0, (size_t)N * 4, stream);
        hipLaunchKernelGGL(hist_rows, dim3((E + 255) / 256), dim3(256), 0, stream, ei, cnt, E);
        hipLaunchKernelGGL(scan_counts, dim3(1), dim3(SCAN_NT), 0, stream, cnt, offs, cur, N);
        hipLaunchKernelGGL(tfn_edge_sorted, dim3((E + 255) / 256), dim3(256), 0, stream,
                           x, pos, ei, T, cur, eout, E);
        hipLaunchKernelGGL(gather_nodes, dim3((N * 32 + 255) / 256), dim3(256), 0, stream,
                           eout, offs, cnt, y, N);
    } else {
        // Fallback: atomics into d_out (works with ws >= table only).
        (void)off_tab_end;
        hipMemsetAsync(y, 0, (size_t)N * 32 * 4, stream);
        hipLaunchKernelGGL(tfn_edge_atomic, dim3((E + 255) / 256), dim3(256), 0, stream,
                           x, pos, ei, T, y, E);
        hipLaunchKernelGGL(finish_silu, dim3((N * 8 + 255) / 256), dim3(256), 0, stream, y, N * 8);
    }
}

// Round 3
// 321.395 us; speedup vs baseline: 3.7545x; 1.1742x over previous
//
#include <hip/hip_runtime.h>
#include <hip/hip_fp16.h>

// ---------------------------------------------------------------------------
// TFN-lite layer, MI355X fp32 implementation, round 3.
//
//  * wa(d) table (320 folded W2 columns) tabulated on 2048-pt grid, fp16.
//  * Edges counting-sorted by row (CSR). Edge kernel runs on sorted edges:
//    a 256-edge block spans ~16 nodes -> accumulate in LDS (stride 33),
//    plain-store contained nodes, global-atomic only boundary nodes.
//  * No 51MB intermediate, no 12.8M global atomics.
// ---------------------------------------------------------------------------

#define INV_S3  0.5773502691896258f   // 1/sqrt(3)
#define A0S     0.1767766952966369f   // 1/sqrt(32)
#define A1S     0.27386127875258306f  // sqrt(3)/sqrt(40)
#define S15     3.872983346207417f    // sqrt(15)
#define S5      2.23606797749979f     // sqrt(5)
#define INV_S10 0.31622776601683794f  // 1/sqrt(10)   (cg121 normalized)
#define INV_S30 0.18257418583505536f  // 1/sqrt(30)

#define TBL   2048
#define DMAX  8.0f
#define BLK   256
#define SPAN  128   // max node range held in LDS per block (256 edges span ~16)

typedef _Float16 half8 __attribute__((ext_vector_type(8)));

// ---------------------------------------------------------------------------
// Fold W2 (64x576) into W2f [k][u*40 + t*8 + wo], 64 rows x 320 cols (fp32).
__global__ void prep_w2(const float* __restrict__ W2, float* __restrict__ W2f) {
    int idx = blockIdx.x * blockDim.x + threadIdx.x;
    if (idx >= 64 * 320) return;
    int k = idx / 320;
    int c = idx - k * 320;
    int u = c / 40;
    int r = c - u * 40;
    int t = r >> 3;
    int wo = r & 7;
    const float* Wk = W2 + k * 576;
    float v;
    if (t < 4) {
        int base = t * 128 + u * 16 + wo;
        v = Wk[base] + Wk[base + 8];
    } else {
        v = Wk[512 + u * 8 + wo];
    }
    W2f[idx] = v;
}

// T[j][c] = wa_c(d_j) in fp16, d_j = j * DMAX/(TBL-1). One block per j.
__global__ void build_table(const float* __restrict__ W1,
                            const float* __restrict__ W2f,
                            _Float16* __restrict__ T) {
    __shared__ float hs[64];
    int j = blockIdx.x;
    float d = (float)j * (DMAX / (float)(TBL - 1));
    int tid = threadIdx.x;
    if (tid < 64) {
        float acc = 0.f;
#pragma unroll
        for (int i = 0; i < 16; ++i) {
            float t = d - (float)i * (1.0f / 3.0f);
            float r = __expf(-4.5f * t * t);
            acc = fmaf(r, W1[i * 64 + tid], acc);
        }
        hs[tid] = fmaxf(acc, 0.f) * 0.25f;   // /sqrt(16)
    }
    __syncthreads();
    float acc = 0.f;
#pragma unroll 4
    for (int k = 0; k < 64; ++k) acc = fmaf(hs[k], W2f[k * 320 + tid], acc);
    T[j * 320 + tid] = (_Float16)acc;
}

// ---------------------------------------------------------------------------
// CSR build
__global__ void hist_rows(const int* __restrict__ ei, int* __restrict__ cnt, int E) {
    int e = blockIdx.x * blockDim.x + threadIdx.x;
    if (e < E) atomicAdd(&cnt[ei[e]], 1);
}

#define SCAN_NT 1024
#define SCAN_L  32   // covers n <= 32768
__global__ void scan_counts(const int* __restrict__ cnt, int* __restrict__ offs,
                            int* __restrict__ cur, int n) {
    __shared__ int sums[SCAN_NT];
    int tid = threadIdx.x;
    int start = tid * SCAN_L;
    int total = 0;
#pragma unroll 4
    for (int i = 0; i < SCAN_L; ++i) {
        int idx = start + i;
        total += (idx < n) ? cnt[idx] : 0;
    }
    sums[tid] = total;
    __syncthreads();
    for (int s = 1; s < SCAN_NT; s <<= 1) {
        int t = (tid >= s) ? sums[tid - s] : 0;
        __syncthreads();
        sums[tid] += t;
        __syncthreads();
    }
    int running = sums[tid] - total;
#pragma unroll 4
    for (int i = 0; i < SCAN_L; ++i) {
        int idx = start + i;
        if (idx < n) {
            offs[idx] = running;
            cur[idx] = running;
            running += cnt[idx];
        }
    }
}

// Scatter (row,col) of each edge to its sorted slot.
__global__ void scatter_edges(const int* __restrict__ ei, int* __restrict__ cur,
                              int* __restrict__ srow, int* __restrict__ scol, int E) {
    int e = blockIdx.x * blockDim.x + threadIdx.x;
    if (e >= E) return;
    int row = ei[e];
    int p = atomicAdd(&cur[row], 1);
    srow[p] = row;
    scol[p] = ei[E + e];
}

// ---------------------------------------------------------------------------
// Main: sorted-edge compute + LDS segment accumulation + node write-out.
__global__ __launch_bounds__(BLK) void edge_block(
    const float* __restrict__ x, const float* __restrict__ pos,
    const int* __restrict__ srow, const int* __restrict__ scol,
    const int* __restrict__ offs, const int* __restrict__ cnt,
    const _Float16* __restrict__ T, float* __restrict__ y, int E) {

    __shared__ float accs[SPAN * 33];
    __shared__ int sh_first;

    int tid = threadIdx.x;
    int bs = blockIdx.x * BLK;
    int be = min(bs + BLK, E);
    int s = bs + tid;

#pragma unroll 4
    for (int i = tid; i < SPAN * 33; i += BLK) accs[i] = 0.f;
    if (tid == 0) sh_first = srow[bs];
    __syncthreads();
    int row_first = sh_first;

    if (s < E) {
        int row = srow[s];
        int col = scol[s];

        float evx = pos[3 * row + 0] - pos[3 * col + 0];
        float evy = pos[3 * row + 1] - pos[3 * col + 1];
        float evz = pos[3 * row + 2] - pos[3 * col + 2];
        float d2 = evx * evx + evy * evy + evz * evz + 1e-12f;
        float d = sqrtf(d2);
        float invd = 1.0f / d;
        float nx = evx * invd, ny = evy * invd, nz = evz * invd;

        float fj = d * ((float)(TBL - 1) / DMAX);
        int j0 = (int)fj;
        if (j0 > TBL - 2) j0 = TBL - 2;
        float t = fminf(fj - (float)j0, 1.0f);
        const _Float16* Arow = T + (size_t)j0 * 320;
        const _Float16* Brow = Arow + 320;

        const float4* xr4 = reinterpret_cast<const float4*>(x + row * 32);
        float4 t0 = xr4[0], t1 = xr4[1];
        float xs[8] = {t0.x, t0.y, t0.z, t0.w, t1.x, t1.y, t1.z, t1.w};
        float xv[24];
        {
            float4 v0_ = xr4[2], v1_ = xr4[3], v2_ = xr4[4], v3_ = xr4[5],
                   v4_ = xr4[6], v5_ = xr4[7];
            xv[0] = v0_.x;  xv[1] = v0_.y;  xv[2] = v0_.z;  xv[3] = v0_.w;
            xv[4] = v1_.x;  xv[5] = v1_.y;  xv[6] = v1_.z;  xv[7] = v1_.w;
            xv[8] = v2_.x;  xv[9] = v2_.y;  xv[10] = v2_.z; xv[11] = v2_.w;
            xv[12] = v3_.x; xv[13] = v3_.y; xv[14] = v3_.z; xv[15] = v3_.w;
            xv[16] = v4_.x; xv[17] = v4_.y; xv[18] = v4_.z; xv[19] = v4_.w;
            xv[20] = v5_.x; xv[21] = v5_.y; xv[22] = v5_.z; xv[23] = v5_.w;
        }

        float Y20 = S15 * nx * nz;
        float Y21 = S15 * nx * ny;
        float Y22 = 0.5f * S5 * (3.f * ny * ny - 1.f);
        float Y23 = S15 * ny * nz;
        float Y24 = 0.5f * S15 * (nz * nz - nx * nx);
        float M00 = -Y22 * INV_S30 - Y24 * INV_S10;
        float M11 = 2.f * Y22 * INV_S30;
        float M22 = -Y22 * INV_S30 + Y24 * INV_S10;
        float M01 = Y21 * INV_S10;
        float M02 = Y20 * INV_S10;
        float M12 = Y23 * INV_S10;

        float s_acc[8], v0a[8], v1a[8], v2a[8];
#pragma unroll
        for (int wo = 0; wo < 8; ++wo) { s_acc[wo] = 0.f; v0a[wo] = 0.f; v1a[wo] = 0.f; v2a[wo] = 0.f; }

#pragma unroll 2
        for (int u = 0; u < 8; ++u) {
            float wa[40];
            const half8* A8 = reinterpret_cast<const half8*>(Arow + u * 40);
            const half8* B8 = reinterpret_cast<const half8*>(Brow + u * 40);
#pragma unroll
            for (int q = 0; q < 5; ++q) {
                half8 a = A8[q], b = B8[q];
#pragma unroll
                for (int z = 0; z < 8; ++z) {
                    float fa = (float)a[z], fb = (float)b[z];
                    wa[q * 8 + z] = fmaf(t, fb - fa, fa);
                }
            }
            float xu = xs[u];
            float a = xv[u * 3 + 0], b = xv[u * 3 + 1], c3 = xv[u * 3 + 2];
            float qu = a * nx + b * ny + c3 * nz;
            float m0 = M00 * a + M01 * b + M02 * c3;
            float m1 = M01 * a + M11 * b + M12 * c3;
            float m2 = M02 * a + M12 * b + M22 * c3;
#pragma unroll
            for (int wo = 0; wo < 8; ++wo) {
                s_acc[wo] = fmaf(xu, wa[wo], s_acc[wo]);
                s_acc[wo] = fmaf(qu, wa[8 + wo], s_acc[wo]);
                float cw = xu * wa[16 + wo];
                v0a[wo] = fmaf(cw, nx, v0a[wo]);
                v1a[wo] = fmaf(cw, ny, v1a[wo]);
                v2a[wo] = fmaf(cw, nz, v2a[wo]);
                float wd = INV_S3 * wa[24 + wo];
                v0a[wo] = fmaf(a, wd, v0a[wo]);
                v1a[wo] = fmaf(b, wd, v1a[wo]);
                v2a[wo] = fmaf(c3, wd, v2a[wo]);
                float we = wa[32 + wo];
                v0a[wo] = fmaf(m0, we, v0a[wo]);
                v1a[wo] = fmaf(m1, we, v1a[wo]);
                v2a[wo] = fmaf(m2, we, v2a[wo]);
            }
        }

        float out[32];
#pragma unroll
        for (int wo = 0; wo < 8; ++wo) out[wo] = A0S * 0.125f * s_acc[wo];
#pragma unroll
        for (int wo = 0; wo < 8; ++wo) {
            out[8 + wo * 3 + 0] = A1S * 0.125f * v0a[wo];
            out[8 + wo * 3 + 1] = A1S * 0.125f * v1a[wo];
            out[8 + wo * 3 + 2] = A1S * 0.125f * v2a[wo];
        }

        int nl = row - row_first;
        if (nl < SPAN) {
            float* dst = accs + nl * 33;
#pragma unroll
            for (int c = 0; c < 32; ++c) atomicAdd(dst + c, out[c]);
        } else {
            // pathological span overflow: direct global atomics (y pre-zeroed)
            float* yr = y + (size_t)row * 32;
#pragma unroll
            for (int c = 0; c < 32; ++c) atomicAdd(yr + c, out[c]);
        }
    }
    __syncthreads();

    // write-out: contained nodes -> plain store; boundary -> global atomic
    int row_last = srow[be - 1];
    int L = min(row_last, row_first + SPAN - 1) - row_first + 1;
    for (int idx = tid; idx < L * 32; idx += BLK) {
        int rl = idx >> 5, c = idx & 31;
        int r = row_first + rl;
        int o = offs[r], k = cnt[r];
        float v = accs[rl * 33 + c];
        if (o >= bs && o + k <= be) {
            y[(size_t)r * 32 + c] = v;
        } else {
            atomicAdd(&y[(size_t)r * 32 + c], v);
        }
    }
}

// In-place silu on first 8 columns of y.
__global__ void finish_silu(float* __restrict__ y, int n8) {
    int i = blockIdx.x * blockDim.x + threadIdx.x;
    if (i >= n8) return;
    int rown = i >> 3, c = i & 7;
    int idx = rown * 32 + c;
    float v = y[idx];
    y[idx] = v / (1.0f + __expf(-v));
}

// ---------------------------------------------------------------------------
extern "C" void kernel_launch(void* const* d_in, const int* in_sizes, int n_in,
                              void* d_out, int out_size, void* d_ws, size_t ws_size,
                              hipStream_t stream) {
    const float* x   = (const float*)d_in[0];
    const float* pos = (const float*)d_in[1];
    const int*   ei  = (const int*)d_in[2];
    const float* W1  = (const float*)d_in[3];
    const float* W2  = (const float*)d_in[4];
    int N = in_sizes[1] / 3;
    int E = in_sizes[2] / 2;

    char* ws = (char*)d_ws;
    size_t off = 0;
    float*    W2f  = (float*)(ws + off);    off += (size_t)64 * 320 * 4;   // 80 KiB
    _Float16* T    = (_Float16*)(ws + off); off += (size_t)TBL * 320 * 2;  // 1.25 MiB
    int*      cnt  = (int*)(ws + off);      off += (size_t)N * 4;
    int*      offs = (int*)(ws + off);      off += (size_t)N * 4;
    int*      cur  = (int*)(ws + off);      off += (size_t)N * 4;
    int*      srow = (int*)(ws + off);      off += (size_t)E * 4;
    int*      scol = (int*)(ws + off);      off += (size_t)E * 4;

    float* y = (float*)d_out;

    hipLaunchKernelGGL(prep_w2, dim3((64 * 320 + 255) / 256), dim3(256), 0, stream, W2, W2f);
    hipLaunchKernelGGL(build_table, dim3(TBL), dim3(320), 0, stream, W1, W2f, T);
    hipMemsetAsync(cnt, 0, (size_t)N * 4, stream);
    hipMemsetAsync(y, 0, (size_t)N * 32 * 4, stream);
    hipLaunchKernelGGL(hist_rows, dim3((E + 255) / 256), dim3(256), 0, stream, ei, cnt, E);
    hipLaunchKernelGGL(scan_counts, dim3(1), dim3(SCAN_NT), 0, stream, cnt, offs, cur, N);
    hipLaunchKernelGGL(scatter_edges, dim3((E + 255) / 256), dim3(256), 0, stream,
                       ei, cur, srow, scol, E);
    hipLaunchKernelGGL(edge_block, dim3((E + BLK - 1) / BLK), dim3(BLK), 0, stream,
                       x, pos, srow, scol, offs, cnt, T, y, E);
    hipLaunchKernelGGL(finish_silu, dim3((N * 8 + 255) / 256), dim3(256), 0, stream, y, N * 8);
}

// Round 4
// 219.602 us; speedup vs baseline: 5.4948x; 1.4635x over previous
//
#include <hip/hip_runtime.h>
#include <hip/hip_fp16.h>

// ---------------------------------------------------------------------------
// TFN-lite layer, MI355X, round 4.
//
//  * wa(d) table, fp16, layout T[j][c'], c' = t*64 + u*8 + wo  (t:5, u:8, wo:8).
//    An 8-lane "edge group" reads each 128B chunk coalesced: instruction t,
//    lane u reads halves [t*64+u*8 .. +8). 20 line-requests/edge vs 80 in R3.
//  * Node-centric main kernel: block(64) = node; lane = g*8+u; group g handles
//    edge g of each round of 8 CSR edges; lane accumulates u=lane%8's
//    contribution over ALL edges; one 6-round shfl_xor butterfly per node;
//    lane 0 stores 32 ch (silu fused). No y memset, no global atomics.
//  * Aux: fused W2-fold+table build (W2 in LDS), LDS-staged 1-block scan.
// ---------------------------------------------------------------------------

#define INV_S3  0.5773502691896258f   // 1/sqrt(3)
#define A0S     0.1767766952966369f   // 1/sqrt(32)
#define A1S     0.27386127875258306f  // sqrt(3)/sqrt(40)
#define S15     3.872983346207417f    // sqrt(15)
#define S5      2.23606797749979f     // sqrt(5)
#define INV_S10 0.31622776601683794f  // 1/sqrt(10)   (cg121 normalized)
#define INV_S30 0.18257418583505536f  // 1/sqrt(30)

#define TBL   2048
#define DMAX  8.0f

typedef _Float16 half8 __attribute__((ext_vector_type(8)));

// ---------------------------------------------------------------------------
// Fused fold+table: T[j][t*64+u*8+wo] = wa(d_j). 256 blocks x 8 rows each.
__global__ __launch_bounds__(320) void build_table_f(
    const float* __restrict__ W1, const float* __restrict__ W2,
    _Float16* __restrict__ T) {
    __shared__ float w2s[64 * 576];   // 147456 B
    __shared__ float hs[64];
    int tid = threadIdx.x;
    for (int i = tid; i < 64 * 576; i += 320) w2s[i] = W2[i];

    int t = tid / 64;                 // wave-uniform (64-lane waves)
    int r = tid % 64;
    int u = r >> 3, wo = r & 7;
    int idx0 = (t < 4) ? (t * 128 + u * 16 + wo) : (512 + u * 8 + wo);
    bool twin = (t < 4);

    for (int jj = 0; jj < 8; ++jj) {
        int j = blockIdx.x * 8 + jj;
        float d = (float)j * (DMAX / (float)(TBL - 1));
        __syncthreads();              // protect hs rewrite (+ first-iter W2 load)
        if (tid < 64) {
            float acc = 0.f;
#pragma unroll
            for (int i = 0; i < 16; ++i) {
                float tt = d - (float)i * (1.0f / 3.0f);
                float rb = __expf(-4.5f * tt * tt);
                acc = fmaf(rb, W1[i * 64 + tid], acc);
            }
            hs[tid] = fmaxf(acc, 0.f) * 0.25f;   // /sqrt(16)
        }
        __syncthreads();
        float acc = 0.f;
#pragma unroll 4
        for (int k = 0; k < 64; ++k) {
            float wv = w2s[k * 576 + idx0];
            if (twin) wv += w2s[k * 576 + idx0 + 8];
            acc = fmaf(hs[k], wv, acc);
        }
        T[(size_t)j * 320 + tid] = (_Float16)acc;
    }
}

// ---------------------------------------------------------------------------
// CSR build
__global__ void hist_rows(const int* __restrict__ ei, int* __restrict__ cnt, int E) {
    int e = blockIdx.x * blockDim.x + threadIdx.x;
    if (e < E) atomicAdd(&cnt[ei[e]], 1);
}

#define SCAN_NT  1024
#define SCAN_CAP 32768
__global__ __launch_bounds__(SCAN_NT) void scan_lds(
    const int* __restrict__ cnt, int* __restrict__ offs,
    int* __restrict__ cur, int n) {
    __shared__ int ld[SCAN_CAP];
    __shared__ int sums[SCAN_NT];
    int tid = threadIdx.x;
    for (int i = tid; i < n; i += SCAN_NT) ld[i] = cnt[i];
    __syncthreads();
    int L = (n + SCAN_NT - 1) / SCAN_NT;
    int start = tid * L;
    int end = min(start + L, n);
    int total = 0;
    for (int i = start; i < end; ++i) total += ld[i];
    sums[tid] = total;
    __syncthreads();
    for (int s = 1; s < SCAN_NT; s <<= 1) {
        int t = (tid >= s) ? sums[tid - s] : 0;
        __syncthreads();
        sums[tid] += t;
        __syncthreads();
    }
    int running = sums[tid] - total;
    for (int i = start; i < end; ++i) { int c = ld[i]; ld[i] = running; running += c; }
    __syncthreads();
    for (int i = tid; i < n; i += SCAN_NT) { int v = ld[i]; offs[i] = v; cur[i] = v; }
}

// Scatter each edge's col to its sorted slot (row implicit via CSR).
__global__ void scatter_edges(const int* __restrict__ ei, int* __restrict__ cur,
                              int* __restrict__ scol, int E) {
    int e = blockIdx.x * blockDim.x + threadIdx.x;
    if (e >= E) return;
    int row = ei[e];
    int p = atomicAdd(&cur[row], 1);
    scol[p] = ei[E + e];
}

// ---------------------------------------------------------------------------
// Main: one block (64 threads) per node.
__global__ __launch_bounds__(64) void tfn_node(
    const float* __restrict__ x, const float* __restrict__ pos,
    const int* __restrict__ scol, const int* __restrict__ offs,
    const int* __restrict__ cnt, const _Float16* __restrict__ T,
    float* __restrict__ y, int N) {

    int n = blockIdx.x;
    int lane = threadIdx.x;       // 0..63
    int g = lane >> 3;            // edge slot within round
    int u = lane & 7;             // this lane's u

    int base = offs[n];
    int kc = cnt[n];

    const float* xr = x + (size_t)n * 32;
    float xu  = xr[u];
    float xv0 = xr[8 + 3 * u + 0];
    float xv1 = xr[8 + 3 * u + 1];
    float xv2 = xr[8 + 3 * u + 2];
    float prx = pos[3 * n + 0], pry = pos[3 * n + 1], prz = pos[3 * n + 2];

    float s_acc[8], va0[8], va1[8], va2[8];
#pragma unroll
    for (int z = 0; z < 8; ++z) { s_acc[z] = 0.f; va0[z] = 0.f; va1[z] = 0.f; va2[z] = 0.f; }

    int rounds = (kc + 7) >> 3;
    for (int rd = 0; rd < rounds; ++rd) {
        int slot = rd * 8 + g;
        if (slot < kc) {
            int col = scol[base + slot];
            float evx = prx - pos[3 * col + 0];
            float evy = pry - pos[3 * col + 1];
            float evz = prz - pos[3 * col + 2];
            float d2 = evx * evx + evy * evy + evz * evz + 1e-12f;
            float invd = rsqrtf(d2);
            float dd = d2 * invd;
            float nx = evx * invd, ny = evy * invd, nz = evz * invd;

            float fj = dd * ((float)(TBL - 1) / DMAX);
            int j0 = (int)fj;
            j0 = min(j0, TBL - 2);
            float tf = fminf(fj - (float)j0, 1.0f);
            _Float16 th = (_Float16)tf;

            const _Float16* Ar = T + (size_t)j0 * 320 + u * 8;
            half8 A[5], B[5];
#pragma unroll
            for (int t = 0; t < 5; ++t) {
                A[t] = *(const half8*)(Ar + t * 64);
                B[t] = *(const half8*)(Ar + 320 + t * 64);
            }

            // u-local features
            float qu = xv0 * nx + xv1 * ny + xv2 * nz;
            float Y22 = 0.5f * S5 * (3.f * ny * ny - 1.f);
            float Y24 = 0.5f * S15 * (nz * nz - nx * nx);
            float M00 = -Y22 * INV_S30 - Y24 * INV_S10;
            float M11 = 2.f * Y22 * INV_S30;
            float M22 = -Y22 * INV_S30 + Y24 * INV_S10;
            float M01 = (S15 * nx * ny) * INV_S10;
            float M02 = (S15 * nx * nz) * INV_S10;
            float M12 = (S15 * ny * nz) * INV_S10;
            float m0 = M00 * xv0 + M01 * xv1 + M02 * xv2;
            float m1 = M01 * xv0 + M11 * xv1 + M12 * xv2;
            float m2 = M02 * xv0 + M12 * xv1 + M22 * xv2;

#pragma unroll
            for (int t = 0; t < 5; ++t) {
                half8 w;
#pragma unroll
                for (int z = 0; z < 8; ++z)
                    w[z] = A[t][z] + (B[t][z] - A[t][z]) * th;  // fp16 lerp
                if (t == 0) {
#pragma unroll
                    for (int z = 0; z < 8; ++z) s_acc[z] = fmaf(xu, (float)w[z], s_acc[z]);
                } else if (t == 1) {
#pragma unroll
                    for (int z = 0; z < 8; ++z) s_acc[z] = fmaf(qu, (float)w[z], s_acc[z]);
                } else if (t == 2) {
#pragma unroll
                    for (int z = 0; z < 8; ++z) {
                        float cw = xu * (float)w[z];
                        va0[z] = fmaf(cw, nx, va0[z]);
                        va1[z] = fmaf(cw, ny, va1[z]);
                        va2[z] = fmaf(cw, nz, va2[z]);
                    }
                } else if (t == 3) {
#pragma unroll
                    for (int z = 0; z < 8; ++z) {
                        float wd = (float)w[z] * INV_S3;
                        va0[z] = fmaf(xv0, wd, va0[z]);
                        va1[z] = fmaf(xv1, wd, va1[z]);
                        va2[z] = fmaf(xv2, wd, va2[z]);
                    }
                } else {
#pragma unroll
                    for (int z = 0; z < 8; ++z) {
                        float we = (float)w[z];
                        va0[z] = fmaf(m0, we, va0[z]);
                        va1[z] = fmaf(m1, we, va1[z]);
                        va2[z] = fmaf(m2, we, va2[z]);
                    }
                }
            }
        }
    }

    // butterfly all-reduce over 64 lanes (sums over u and edge-groups)
#pragma unroll
    for (int m = 1; m < 64; m <<= 1) {
#pragma unroll
        for (int z = 0; z < 8; ++z) {
            s_acc[z] += __shfl_xor(s_acc[z], m, 64);
            va0[z]   += __shfl_xor(va0[z], m, 64);
            va1[z]   += __shfl_xor(va1[z], m, 64);
            va2[z]   += __shfl_xor(va2[z], m, 64);
        }
    }

    if (lane == 0) {
        float s[8], w0[8], w1[8], w2[8];
#pragma unroll
        for (int z = 0; z < 8; ++z) {
            float v = A0S * 0.125f * s_acc[z];
            s[z] = v / (1.0f + __expf(-v));       // silu
            w0[z] = A1S * 0.125f * va0[z];
            w1[z] = A1S * 0.125f * va1[z];
            w2[z] = A1S * 0.125f * va2[z];
        }
        float4* yo = reinterpret_cast<float4*>(y + (size_t)n * 32);
        yo[0] = make_float4(s[0], s[1], s[2], s[3]);
        yo[1] = make_float4(s[4], s[5], s[6], s[7]);
        yo[2] = make_float4(w0[0], w1[0], w2[0], w0[1]);
        yo[3] = make_float4(w1[1], w2[1], w0[2], w1[2]);
        yo[4] = make_float4(w2[2], w0[3], w1[3], w2[3]);
        yo[5] = make_float4(w0[4], w1[4], w2[4], w0[5]);
        yo[6] = make_float4(w1[5], w2[5], w0[6], w1[6]);
        yo[7] = make_float4(w2[6], w0[7], w1[7], w2[7]);
    }
}

// ---------------------------------------------------------------------------
extern "C" void kernel_launch(void* const* d_in, const int* in_sizes, int n_in,
                              void* d_out, int out_size, void* d_ws, size_t ws_size,
                              hipStream_t stream) {
    const float* x   = (const float*)d_in[0];
    const float* pos = (const float*)d_in[1];
    const int*   ei  = (const int*)d_in[2];
    const float* W1  = (const float*)d_in[3];
    const float* W2  = (const float*)d_in[4];
    int N = in_sizes[1] / 3;
    int E = in_sizes[2] / 2;

    char* ws = (char*)d_ws;
    size_t off = 0;
    _Float16* T    = (_Float16*)(ws + off); off += (size_t)TBL * 320 * 2;  // 1.31 MB
    int*      cnt  = (int*)(ws + off);      off += (size_t)N * 4;
    int*      offs = (int*)(ws + off);      off += (size_t)N * 4;
    int*      cur  = (int*)(ws + off);      off += (size_t)N * 4;
    int*      scol = (int*)(ws + off);      off += (size_t)E * 4;

    float* y = (float*)d_out;

    hipLaunchKernelGGL(build_table_f, dim3(TBL / 8), dim3(320), 0, stream, W1, W2, T);
    hipMemsetAsync(cnt, 0, (size_t)N * 4, stream);
    hipLaunchKernelGGL(hist_rows, dim3((E + 255) / 256), dim3(256), 0, stream, ei, cnt, E);
    hipLaunchKernelGGL(scan_lds, dim3(1), dim3(SCAN_NT), 0, stream, cnt, offs, cur, N);
    hipLaunchKernelGGL(scatter_edges, dim3((E + 255) / 256), dim3(256), 0, stream,
                       ei, cur, scol, E);
    hipLaunchKernelGGL(tfn_node, dim3(N), dim3(64), 0, stream,
                       x, pos, scol, offs, cnt, T, y, N);
}